// Round 5
// baseline (1645.511 us; speedup 1.0000x reference)
//
#include <hip/hip_runtime.h>

#define BB 4
#define NN 4096
#define DD 256
#define KK 16
#define PTS 2
#define SA 264   // bufA/bufB/kf/vf row stride (bf16)

typedef __bf16 bf16;
typedef __attribute__((ext_vector_type(8))) __bf16 bf16x8;
typedef __attribute__((ext_vector_type(4))) __bf16 bf16x4;
typedef __attribute__((ext_vector_type(4))) float f32x4;

#define KROWS 8     // rows per knn block (2 per wave)
#define KNNB (BB * NN / KROWS)  // 2048
#define PROJB 256   // proj blocks (64 rows each)
#define PREPB 256   // prep blocks

// packed squared distance: (dist_bits+1) << 32 | j  — index in low 32 bits is
// EXACT, so selection bookkeeping below never depends on FP re-comparison.
__device__ __forceinline__ unsigned long long distpack(float xi, float yi,
                                                       float zi, float xj,
                                                       float yj, float zj,
                                                       int j) {
  const float dx = xi - xj, dy = yi - yj, dz = zi - zj;
  const float d = fmaf(dz, dz, fmaf(dy, dy, dx * dx));
  return (((unsigned long long)__float_as_uint(d) + 1ull) << 32) |
         (unsigned int)j;
}

// ---------------------------------------------------------------------------
// knn_kernel v3: scratch-free AND recompute-robust.
//  - per-thread state is named scalars only (g0..g7, removed) -> no local-mem
//    demotion possible (R3's gm[8] scratch cost 1.19 GB HBM / 466 us).
//  - extraction excludes candidates by INDEX BITMASK (removed, 1 bit per
//    candidate slot), not by value ordering -> correctness no longer depends
//    on bit-identical FP between build and recompute sites (R4 fragility).
//    Ulp-level mismatch can only reorder near-ties; output is invariant
//    under k-permutation (softmax+einsum over k are symmetric).
// ---------------------------------------------------------------------------
__global__ __launch_bounds__(256, 3) void knn_kernel(
    const float* __restrict__ xyz, int* __restrict__ knn) {
  const int t = threadIdx.x;
  const int lane = t & 63;
  const int wv = t >> 6;
  const int row_base = blockIdx.x * KROWS;
  const int b = row_base >> 12;

  __shared__ float xs[NN], ys[NN], zs[NN];  // 48 KB SoA
  const float* xb = xyz + (size_t)b * NN * 3;
  for (int e = t; e < NN * 3; e += 256) {
    const int idx = e / 3;
    const int ax = e - idx * 3;
    const float v = xb[e];
    if (ax == 0) xs[idx] = v;
    else if (ax == 1) ys[idx] = v;
    else zs[idx] = v;
  }
  __syncthreads();

  for (int rr = 0; rr < KROWS / 4; ++rr) {
    const int row = row_base + rr * 4 + wv;
    const int i = row & (NN - 1);
    const float xi = xs[i], yi = ys[i], zi = zs[i];

    // ---- build: per-group running minima in 8 named scalar u64s ----
    // lane's candidate slot c (0..63) is point j = c*64 + lane; group g=c>>3.
    unsigned long long g0, g1, g2, g3, g4, g5, g6, g7;
#define KNN_BUILD(G, DST)                                          \
  {                                                                \
    unsigned long long mn = ~0ull;                                 \
    _Pragma("unroll") for (int s = 0; s < 8; ++s) {                \
      const int j = ((G) * 8 + s) * 64 + lane;                     \
      const unsigned long long v =                                 \
          distpack(xi, yi, zi, xs[j], ys[j], zs[j], j);            \
      if (v < mn) mn = v;                                          \
    }                                                              \
    DST = mn;                                                      \
  }
    KNN_BUILD(0, g0) KNN_BUILD(1, g1) KNN_BUILD(2, g2) KNN_BUILD(3, g3)
    KNN_BUILD(4, g4) KNN_BUILD(5, g5) KNN_BUILD(6, g6) KNN_BUILD(7, g7)
#undef KNN_BUILD

    // ---- 16 extraction rounds, index-mask exclusion ----
    unsigned long long removed = 0ull;  // bit c: this lane's slot c extracted
    unsigned int myj = 0u;
    for (int r = 0; r < KK; ++r) {
      unsigned long long lmin = g0;
      if (g1 < lmin) lmin = g1;
      if (g2 < lmin) lmin = g2;
      if (g3 < lmin) lmin = g3;
      if (g4 < lmin) lmin = g4;
      if (g5 < lmin) lmin = g5;
      if (g6 < lmin) lmin = g6;
      if (g7 < lmin) lmin = g7;
#pragma unroll
      for (int off = 1; off < 64; off <<= 1) {
        const unsigned long long o = __shfl_xor(lmin, off);
        if (o < lmin) lmin = o;
      }
      const unsigned int jext = (unsigned int)lmin;  // exact extracted index
      if (lane == r) myj = jext;
      const int owner = (int)(jext & 63u);  // lane owning this candidate
      const int cext = (int)(jext >> 6);    // its slot 0..63
      if (lane == owner) removed |= (1ull << cext);
      // recompute ONLY the owner's group (uniform across wave); all lanes
      // compute over their own slots with their own mask, only owner stores.
      unsigned long long nm = ~0ull;
#define KNN_RECOMP(G)                                              \
  {                                                                \
    _Pragma("unroll") for (int s = 0; s < 8; ++s) {                \
      const int c = (G) * 8 + s;                                   \
      if (!((removed >> c) & 1ull)) {                              \
        const int j = c * 64 + lane;                               \
        const unsigned long long v =                               \
            distpack(xi, yi, zi, xs[j], ys[j], zs[j], j);          \
        if (v < nm) nm = v;                                        \
      }                                                            \
    }                                                              \
  }
      switch (cext >> 3) {
        case 0: KNN_RECOMP(0); if (lane == owner) g0 = nm; break;
        case 1: KNN_RECOMP(1); if (lane == owner) g1 = nm; break;
        case 2: KNN_RECOMP(2); if (lane == owner) g2 = nm; break;
        case 3: KNN_RECOMP(3); if (lane == owner) g3 = nm; break;
        case 4: KNN_RECOMP(4); if (lane == owner) g4 = nm; break;
        case 5: KNN_RECOMP(5); if (lane == owner) g5 = nm; break;
        case 6: KNN_RECOMP(6); if (lane == owner) g6 = nm; break;
        default: KNN_RECOMP(7); if (lane == owner) g7 = nm; break;
      }
#undef KNN_RECOMP
    }
    if (lane < KK) knn[row * KK + lane] = (int)myj;
  }
}

// ---------------------------------------------------------------------------
// proj_kernel: q/k/v projections, 64 rows/block (unchanged from R3, passed).
// ---------------------------------------------------------------------------
__global__ __launch_bounds__(256, 2) void proj_kernel(
    const float* __restrict__ feats, const float* __restrict__ w_q,
    const float* __restrict__ w_k, const float* __restrict__ w_v,
    bf16* __restrict__ qb, bf16* __restrict__ kfb, bf16* __restrict__ vfb) {
  const int t = threadIdx.x;
  __shared__ __align__(16) bf16 fs[64][SA];  // 33.8 KB
  const int lane = t & 63, wv = t >> 6;
  const int m = lane & 15, qd = lane >> 4;
  const size_t r0 = (size_t)blockIdx.x * 64;
  const float4* f4 = (const float4*)(feats + r0 * DD);
#pragma unroll
  for (int i = 0; i < 16; ++i) {
    const int e = i * 256 + t;
    const float4 v = f4[e];
    bf16x4 w;
    w[0] = (bf16)v.x; w[1] = (bf16)v.y; w[2] = (bf16)v.z; w[3] = (bf16)v.w;
    *(bf16x4*)&fs[e >> 6][(e & 63) * 4] = w;
  }
  __syncthreads();
  bf16x8 afrag[8];
#pragma unroll
  for (int f = 0; f < 8; ++f)
    afrag[f] = *(const bf16x8*)&fs[wv * 16 + m][f * 32 + qd * 8];
  const float* wmat[3] = {w_q, w_k, w_v};
  bf16* omat[3] = {qb, kfb, vfb};
  for (int mat = 0; mat < 3; ++mat) {
    const float* wb = wmat[mat];
    for (int nt = 0; nt < 16; ++nt) {
      const int n = nt * 16 + m;
      bf16x8 bfr[8];
#pragma unroll
      for (int f = 0; f < 8; ++f) {
        const float4 wa =
            *(const float4*)(wb + (size_t)n * DD + f * 32 + qd * 8);
        const float4 wc =
            *(const float4*)(wb + (size_t)n * DD + f * 32 + qd * 8 + 4);
        bf16x8 x;
        x[0] = (bf16)wa.x; x[1] = (bf16)wa.y; x[2] = (bf16)wa.z; x[3] = (bf16)wa.w;
        x[4] = (bf16)wc.x; x[5] = (bf16)wc.y; x[6] = (bf16)wc.z; x[7] = (bf16)wc.w;
        bfr[f] = x;
      }
      f32x4 c = {0.f, 0.f, 0.f, 0.f};
#pragma unroll
      for (int f = 0; f < 8; ++f)
        c = __builtin_amdgcn_mfma_f32_16x16x32_bf16(afrag[f], bfr[f], c, 0, 0, 0);
#pragma unroll
      for (int rr = 0; rr < 4; ++rr)
        omat[mat][(r0 + wv * 16 + qd * 4 + rr) * DD + n] = (bf16)c[rr];
    }
  }
}

// ---------------------------------------------------------------------------
// prep_kernel: weight conversions + sums/sumsq zeroing (unchanged from R3).
// ---------------------------------------------------------------------------
__global__ __launch_bounds__(256) void prep_kernel(
    const float* __restrict__ g_w1, const float* __restrict__ g_w2,
    const float* __restrict__ pe_w, bf16* __restrict__ w1b,
    bf16* __restrict__ w2b, bf16* __restrict__ pwb,
    float* __restrict__ sums) {
  const int idx = blockIdx.x * 256 + threadIdx.x;  // 65536
  w1b[idx] = (bf16)g_w1[idx];
  w2b[idx] = (bf16)g_w2[idx];
  if (idx < 256 * 64) {
    const int n = idx >> 6, c = idx & 63;
    pwb[idx] = (c < 33) ? (bf16)pe_w[n * 33 + c] : (bf16)0.f;
  }
  if (idx < 2 * DD) sums[idx] = 0.f;
}

// per-lane positional-embedding value for column c (0..32; >32 -> 0)
__device__ __forceinline__ float embval(int c, float pd0, float pd1, float pd2) {
  if (c > 32) return 0.f;
  const int cm = c - 3;
  const int ax = (c < 3) ? c : cm % 3;
  const float pdv = (ax == 0) ? pd0 : ((ax == 1) ? pd1 : pd2);
  if (c < 3) return pdv;
  const int f = cm / 6;
  const float x = pdv * fmaf(7.75f, (float)f, 1.0f);  // linspace(1,32,5)
  return ((cm % 6) < 3) ? __sinf(x) : __cosf(x);
}

// ---------------------------------------------------------------------------
// edge_v9 (verbatim round-0 version, measured 345 us): PTS=2, 3 blocks/CU.
// R2 lesson: PTS=1 halves per-phase ILP and regresses 1.7x despite 2x
// occupancy — keep per-phase MFMA work at PTS=2.
// ---------------------------------------------------------------------------
__global__ __launch_bounds__(256, 3) void edge_v9(
    const float* __restrict__ xyz, const float* __restrict__ feats,
    const bf16* __restrict__ qb, const bf16* __restrict__ kfb,
    const bf16* __restrict__ vfb, const int* __restrict__ knn,
    const bf16* __restrict__ w1b, const float* __restrict__ g_b1,
    const bf16* __restrict__ w2b, const float* __restrict__ g_b2,
    const bf16* __restrict__ pwb, const float* __restrict__ pe_b,
    float* __restrict__ res, float* __restrict__ sums,
    float* __restrict__ sumsq) {
  const int t = threadIdx.x;
  const int lane = t & 63;
  const int wv = t >> 6;
  const int m = lane & 15;
  const int qd = lane >> 4;
  const int row0 = blockIdx.x * PTS;
  const int b = row0 >> 12;

  __shared__ __align__(16) bf16 bufA[PTS][16][SA];        // edges
  __shared__ __align__(16) char un_s[PTS * 16 * SA * 2];  // kf_s | bufB(h)
  bf16(*bufB)[16][SA] = (bf16(*)[16][SA])un_s;
  bf16(*kf_s)[16][SA] = (bf16(*)[16][SA])un_s;
  __shared__ __align__(16) bf16 vf_s[PTS][16][SA];
  __shared__ int js_s[PTS][16];

  if (t < PTS * 16) js_s[t >> 4][t & 15] = knn[(row0 + (t >> 4)) * KK + (t & 15)];
  __syncthreads();

  // ---- stage kf_s and vf_s via 16B vector loads (1024 chunks each) ----
#pragma unroll
  for (int i = 0; i < PTS * 2; ++i) {
    const int e = i * 256 + t;
    const int p = e >> 9, rem = e & 511;
    const int k = rem >> 5, ch = rem & 31;
    const size_t base = ((size_t)(b * NN + js_s[p][k])) * DD + ch * 8;
    *(bf16x8*)&kf_s[p][k][ch * 8] = *(const bf16x8*)(kfb + base);
    *(bf16x8*)&vf_s[p][k][ch * 8] = *(const bf16x8*)(vfb + base);
  }

  // ---- emb A-fragments computed per-lane in registers (no LDS) ----
  const float* xb = xyz + (size_t)b * NN * 3;
  bf16x8 ea0[PTS], ea1[PTS];
#pragma unroll
  for (int p = 0; p < PTS; ++p) {
    const int i = (row0 + p) & (NN - 1);
    const int j = js_s[p][m];  // this lane's neighbor row
    const float pd0 = xb[i * 3 + 0] - xb[j * 3 + 0];
    const float pd1 = xb[i * 3 + 1] - xb[j * 3 + 1];
    const float pd2 = xb[i * 3 + 2] - xb[j * 3 + 2];
#pragma unroll
    for (int jj = 0; jj < 8; ++jj) {
      ea0[p][jj] = (bf16)embval(qd * 8 + jj, pd0, pd1, pd2);
      ea1[p][jj] = (bf16)embval(32 + qd * 8 + jj, pd0, pd1, pd2);
    }
  }
  __syncthreads();  // staging visible

  // ---- phase B: pe MFMA -> bufA = q - kf_s + pe ; pe kept in regs ----
  float pe_r[4][PTS][4];
#pragma unroll
  for (int tt = 0; tt < 4; ++tt) {
    const int n = wv * 64 + tt * 16 + m;
    const bf16x8 b0 = *(const bf16x8*)(pwb + (size_t)n * 64 + qd * 8);
    const bf16x8 b1 = *(const bf16x8*)(pwb + (size_t)n * 64 + 32 + qd * 8);
    const float bias = pe_b[n];
#pragma unroll
    for (int p = 0; p < PTS; ++p) {
      f32x4 c = {bias, bias, bias, bias};
      c = __builtin_amdgcn_mfma_f32_16x16x32_bf16(ea0[p], b0, c, 0, 0, 0);
      c = __builtin_amdgcn_mfma_f32_16x16x32_bf16(ea1[p], b1, c, 0, 0, 0);
      const float qv = (float)qb[(size_t)(row0 + p) * DD + n];
#pragma unroll
      for (int rr = 0; rr < 4; ++rr) {
        const int krow = qd * 4 + rr;
        bufA[p][krow][n] = (bf16)(qv - (float)kf_s[p][krow][n] + c[rr]);
        pe_r[tt][p][rr] = c[rr];
      }
    }
  }
  __syncthreads();  // bufA ready; kf_s dead (union -> bufB safe)

  // ---- layer 1: h = relu(edges @ W1^T + b1), bufA -> bufB ----
  {
    bf16x8 afrag[PTS][8];
#pragma unroll
    for (int p = 0; p < PTS; ++p)
#pragma unroll
      for (int f = 0; f < 8; ++f)
        afrag[p][f] = *(const bf16x8*)&bufA[p][m][f * 32 + qd * 8];
    for (int tt = 0; tt < 4; ++tt) {
      const int n = wv * 64 + tt * 16 + m;
      bf16x8 bfr[8];
#pragma unroll
      for (int f = 0; f < 8; ++f)
        bfr[f] = *(const bf16x8*)(w1b + (size_t)n * DD + f * 32 + qd * 8);
      const float bias = g_b1[n];
#pragma unroll
      for (int p = 0; p < PTS; ++p) {
        f32x4 c = {bias, bias, bias, bias};
#pragma unroll
        for (int f = 0; f < 8; ++f)
          c = __builtin_amdgcn_mfma_f32_16x16x32_bf16(afrag[p][f], bfr[f], c, 0, 0, 0);
#pragma unroll
        for (int rr = 0; rr < 4; ++rr)
          bufB[p][qd * 4 + rr][n] = (bf16)fmaxf(c[rr], 0.f);
      }
    }
  }
  __syncthreads();

  // ---- layer 2 + softmax over k + combine (vf_s + pe_r) + BN stats ----
  {
    bf16x8 afrag[PTS][8];
#pragma unroll
    for (int p = 0; p < PTS; ++p)
#pragma unroll
      for (int f = 0; f < 8; ++f)
        afrag[p][f] = *(const bf16x8*)&bufB[p][m][f * 32 + qd * 8];
#pragma unroll
    for (int tt = 0; tt < 4; ++tt) {
      const int n = wv * 64 + tt * 16 + m;
      bf16x8 bfr[8];
#pragma unroll
      for (int f = 0; f < 8; ++f)
        bfr[f] = *(const bf16x8*)(w2b + (size_t)n * DD + f * 32 + qd * 8);
      const float bias = g_b2[n];
      float bs = 0.f, bs2 = 0.f;
#pragma unroll
      for (int p = 0; p < PTS; ++p) {
        f32x4 c = {bias, bias, bias, bias};
#pragma unroll
        for (int f = 0; f < 8; ++f)
          c = __builtin_amdgcn_mfma_f32_16x16x32_bf16(afrag[p][f], bfr[f], c, 0, 0, 0);
        float mx = fmaxf(fmaxf(c[0], c[1]), fmaxf(c[2], c[3]));
        mx = fmaxf(mx, __shfl_xor(mx, 16));
        mx = fmaxf(mx, __shfl_xor(mx, 32));
        float e[4], den = 0.f;
#pragma unroll
        for (int rr = 0; rr < 4; ++rr) {
          e[rr] = __expf(c[rr] - mx);
          den += e[rr];
        }
        den += __shfl_xor(den, 16);
        den += __shfl_xor(den, 32);
        float num = 0.f;
#pragma unroll
        for (int rr = 0; rr < 4; ++rr) {
          const float vpe =
              (float)vf_s[p][qd * 4 + rr][n] + pe_r[tt][p][rr];
          num += e[rr] * vpe;
        }
        num += __shfl_xor(num, 16);
        num += __shfl_xor(num, 32);
        if (qd == 0) {
          const size_t o = (size_t)(row0 + p) * DD + n;
          const float out = num / den + feats[o];
          res[o] = out;
          bs += out;
          bs2 += out * out;
        }
      }
      if (qd == 0) {
        atomicAdd(&sums[n], bs);
        atomicAdd(&sumsq[n], bs2);
      }
    }
  }
}

// ---------------------------------------------------------------------------
// BatchNorm apply (stats accumulated by edge_v9's epilogue)
// ---------------------------------------------------------------------------
__global__ __launch_bounds__(256) void bn_apply(float* __restrict__ out,
                                                const float* __restrict__ sums,
                                                const float* __restrict__ sumsq,
                                                const float* __restrict__ bn_w,
                                                const float* __restrict__ bn_b) {
  const int idx = blockIdx.x * 256 + threadIdx.x;
  const int c = idx & (DD - 1);
  const float inv_n = 1.f / (float)(BB * NN);
  const float mean = sums[c] * inv_n;
  const float var = sumsq[c] * inv_n - mean * mean;
  const float v = out[idx];
  out[idx] = (v - mean) * rsqrtf(var + 1e-5f) * bn_w[c] + bn_b[c];
}

extern "C" void kernel_launch(void* const* d_in, const int* in_sizes, int n_in,
                              void* d_out, int out_size, void* d_ws,
                              size_t ws_size, hipStream_t stream) {
  (void)in_sizes; (void)n_in; (void)out_size; (void)ws_size;
  const float* xyz = (const float*)d_in[0];
  const float* feats = (const float*)d_in[1];
  const float* w_q = (const float*)d_in[2];
  const float* w_k = (const float*)d_in[3];
  const float* w_v = (const float*)d_in[4];
  const float* g_w1 = (const float*)d_in[5];
  const float* g_b1 = (const float*)d_in[6];
  const float* g_w2 = (const float*)d_in[7];
  const float* g_b2 = (const float*)d_in[8];
  const float* pe_w = (const float*)d_in[9];
  const float* pe_b = (const float*)d_in[10];
  const float* bn_w = (const float*)d_in[11];
  const float* bn_b = (const float*)d_in[12];
  float* out = (float*)d_out;

  const int BN = BB * NN;  // 16384
  char* w = (char*)d_ws;
  int* knn = (int*)w;       w += (size_t)BN * KK * 4;
  bf16* qb = (bf16*)w;      w += (size_t)BN * DD * 2;
  bf16* kfb = (bf16*)w;     w += (size_t)BN * DD * 2;
  bf16* vfb = (bf16*)w;     w += (size_t)BN * DD * 2;
  float* sums = (float*)w;  w += DD * 4;
  float* sumsq = (float*)w; w += DD * 4;
  bf16* w1b = (bf16*)w;     w += (size_t)DD * DD * 2;
  bf16* w2b = (bf16*)w;     w += (size_t)DD * DD * 2;
  bf16* pwb = (bf16*)w;     w += (size_t)DD * 64 * 2;

  knn_kernel<<<KNNB, 256, 0, stream>>>(xyz, knn);
  proj_kernel<<<PROJB, 256, 0, stream>>>(feats, w_q, w_k, w_v, qb, kfb, vfb);
  prep_kernel<<<PREPB, 256, 0, stream>>>(g_w1, g_w2, pe_w, w1b, w2b, pwb,
                                         sums);
  edge_v9<<<BN / PTS, 256, 0, stream>>>(xyz, feats, qb, kfb, vfb, knn, w1b,
                                        g_b1, w2b, g_b2, pwb, pe_b, out, sums,
                                        sumsq);
  bn_apply<<<BN, 256, 0, stream>>>(out, sums, sumsq, bn_w, bn_b);
}

// Round 7
// 768.987 us; speedup vs baseline: 2.1398x; 2.1398x over previous
//
#include <hip/hip_runtime.h>

#define BB 4
#define NN 4096
#define DD 256
#define KK 16
#define PTS 2
#define SA 264   // bufA/bufB/kf/vf row stride (bf16)

typedef __bf16 bf16;
typedef __attribute__((ext_vector_type(8))) __bf16 bf16x8;
typedef __attribute__((ext_vector_type(4))) __bf16 bf16x4;
typedef __attribute__((ext_vector_type(4))) float f32x4;

#define KROWS 8     // rows per knn block (2 per wave)
#define KNNB (BB * NN / KROWS)  // 2048
#define PROJB 256   // proj blocks (64 rows each)
#define PREPB 256   // prep blocks

// packed squared distance: (dist_bits+1) << 32 | j  — index in low 32 bits is
// EXACT; all selection bookkeeping is by index, never by FP re-comparison.
__device__ __forceinline__ unsigned long long distpack(float xi, float yi,
                                                       float zi, float xj,
                                                       float yj, float zj,
                                                       int j) {
  const float dx = xi - xj, dy = yi - yj, dz = zi - zj;
  const float d = fmaf(dz, dz, fmaf(dy, dy, dx * dx));
  return (((unsigned long long)__float_as_uint(d) + 1ull) << 32) |
         (unsigned int)j;
}

// ---------------------------------------------------------------------------
// knn_kernel v5: LDS-resident selection state (scratch demotion impossible;
// R3 private array -> 1.19 GB scratch, R5 named scalars -> 3.05 GB scratch),
// with R6's two crash vectors removed:
//  - wave-min reduce via u64 __shfl_xor (register-based; R6's un-fenced LDS
//    butterfly had compiler-invisible cross-lane deps -> reordered -> garbage
//    index -> OOB LDS write -> abort)
//  - all derived indices masked to their domains (bug => wrong answer, not
//    fault); LDS total 58 KB < 64 KB (hedges per-WG static-LDS limit)
// Layout: 4 groups x 16 slots per lane. gm_s[wave][group][lane] = per-lane
// group minima; rm_s[wave][lane] = removed-slot bitmask (index-exact
// exclusion -> no dependence on bit-identical FP recompute; ulp ties only
// permute k, and softmax+einsum over k are permutation-invariant).
// ---------------------------------------------------------------------------
__global__ __launch_bounds__(256, 2) void knn_kernel(
    const float* __restrict__ xyz, int* __restrict__ knn) {
  const int t = threadIdx.x;
  const int lane = t & 63;
  const int wv = t >> 6;
  const int row_base = blockIdx.x * KROWS;
  const int b = row_base >> 12;

  __shared__ float xs[NN], ys[NN], zs[NN];       // 48 KB SoA
  __shared__ unsigned long long gm_s[4][4][64];  // 8 KB
  __shared__ unsigned long long rm_s[4][64];     // 2 KB

  const float* xb = xyz + (size_t)b * NN * 3;
  for (int e = t; e < NN * 3; e += 256) {
    const int idx = e / 3;
    const int ax = e - idx * 3;
    const float v = xb[e];
    if (ax == 0) xs[idx] = v;
    else if (ax == 1) ys[idx] = v;
    else zs[idx] = v;
  }
  __syncthreads();

  for (int rr = 0; rr < KROWS / 4; ++rr) {
    const int row = row_base + rr * 4 + wv;
    const int i = row & (NN - 1);
    const float xi = xs[i], yi = ys[i], zi = zs[i];

    rm_s[wv][lane] = 0ull;

    // ---- build: per-lane per-group minima -> gm_s (only LDS state) ----
    for (int g = 0; g < 4; ++g) {
      unsigned long long mn = ~0ull;
#pragma unroll
      for (int s = 0; s < 16; ++s) {
        const int j = (g * 16 + s) * 64 + lane;
        const unsigned long long v =
            distpack(xi, yi, zi, xs[j], ys[j], zs[j], j);
        if (v < mn) mn = v;
      }
      gm_s[wv][g][lane] = mn;
    }

    // ---- 16 extraction rounds ----
    for (int r = 0; r < KK; ++r) {
      // per-lane min over its 4 groups (short-lived register temp)
      unsigned long long mn = gm_s[wv][0][lane];
      {
        const unsigned long long v1 = gm_s[wv][1][lane];
        if (v1 < mn) mn = v1;
        const unsigned long long v2 = gm_s[wv][2][lane];
        if (v2 < mn) mn = v2;
        const unsigned long long v3 = gm_s[wv][3][lane];
        if (v3 < mn) mn = v3;
      }
      // wave-min butterfly in registers (shfl is ordering-safe; this exact
      // u64 reduce passed correctness in R3/R5)
#pragma unroll
      for (int off = 1; off < 64; off <<= 1) {
        const unsigned long long o = __shfl_xor(mn, off);
        if (o < mn) mn = o;
      }
      const unsigned int jext = (unsigned int)mn;  // extracted point index
      if (lane == 0) knn[row * KK + r] = (int)(jext & (NN - 1));

      const int owner = (int)(jext & 63u);         // lane owning candidate
      const int cext = (int)((jext >> 6) & 63u);   // its slot, bounded 0..63
      const int g = cext >> 4;                     // wave-uniform group 0..3

      // owner marks its slot removed (same-address RMW, program-ordered)
      unsigned long long msk = rm_s[wv][lane];
      if (lane == owner) {
        msk |= (1ull << cext);
        rm_s[wv][lane] = msk;
      }
      // all lanes recompute their own group-g min over non-removed slots
      // (only owner's changed; wave-wide recompute avoids divergence)
      unsigned long long nm = ~0ull;
#pragma unroll
      for (int s = 0; s < 16; ++s) {
        const int c2 = g * 16 + s;
        if (!((msk >> c2) & 1ull)) {
          const int j = c2 * 64 + lane;
          const unsigned long long v =
              distpack(xi, yi, zi, xs[j], ys[j], zs[j], j);
          if (v < nm) nm = v;
        }
      }
      gm_s[wv][g][lane] = nm;
    }
  }
}

// ---------------------------------------------------------------------------
// proj_kernel: q/k/v projections, 64 rows/block (unchanged, passed R3/R5).
// ---------------------------------------------------------------------------
__global__ __launch_bounds__(256, 2) void proj_kernel(
    const float* __restrict__ feats, const float* __restrict__ w_q,
    const float* __restrict__ w_k, const float* __restrict__ w_v,
    bf16* __restrict__ qb, bf16* __restrict__ kfb, bf16* __restrict__ vfb) {
  const int t = threadIdx.x;
  __shared__ __align__(16) bf16 fs[64][SA];  // 33.8 KB
  const int lane = t & 63, wv = t >> 6;
  const int m = lane & 15, qd = lane >> 4;
  const size_t r0 = (size_t)blockIdx.x * 64;
  const float4* f4 = (const float4*)(feats + r0 * DD);
#pragma unroll
  for (int i = 0; i < 16; ++i) {
    const int e = i * 256 + t;
    const float4 v = f4[e];
    bf16x4 w;
    w[0] = (bf16)v.x; w[1] = (bf16)v.y; w[2] = (bf16)v.z; w[3] = (bf16)v.w;
    *(bf16x4*)&fs[e >> 6][(e & 63) * 4] = w;
  }
  __syncthreads();
  bf16x8 afrag[8];
#pragma unroll
  for (int f = 0; f < 8; ++f)
    afrag[f] = *(const bf16x8*)&fs[wv * 16 + m][f * 32 + qd * 8];
  const float* wmat[3] = {w_q, w_k, w_v};
  bf16* omat[3] = {qb, kfb, vfb};
  for (int mat = 0; mat < 3; ++mat) {
    const float* wb = wmat[mat];
    for (int nt = 0; nt < 16; ++nt) {
      const int n = nt * 16 + m;
      bf16x8 bfr[8];
#pragma unroll
      for (int f = 0; f < 8; ++f) {
        const float4 wa =
            *(const float4*)(wb + (size_t)n * DD + f * 32 + qd * 8);
        const float4 wc =
            *(const float4*)(wb + (size_t)n * DD + f * 32 + qd * 8 + 4);
        bf16x8 x;
        x[0] = (bf16)wa.x; x[1] = (bf16)wa.y; x[2] = (bf16)wa.z; x[3] = (bf16)wa.w;
        x[4] = (bf16)wc.x; x[5] = (bf16)wc.y; x[6] = (bf16)wc.z; x[7] = (bf16)wc.w;
        bfr[f] = x;
      }
      f32x4 c = {0.f, 0.f, 0.f, 0.f};
#pragma unroll
      for (int f = 0; f < 8; ++f)
        c = __builtin_amdgcn_mfma_f32_16x16x32_bf16(afrag[f], bfr[f], c, 0, 0, 0);
#pragma unroll
      for (int rr = 0; rr < 4; ++rr)
        omat[mat][(r0 + wv * 16 + qd * 4 + rr) * DD + n] = (bf16)c[rr];
    }
  }
}

// ---------------------------------------------------------------------------
// prep_kernel: weight conversions + sums/sumsq zeroing (unchanged).
// ---------------------------------------------------------------------------
__global__ __launch_bounds__(256) void prep_kernel(
    const float* __restrict__ g_w1, const float* __restrict__ g_w2,
    const float* __restrict__ pe_w, bf16* __restrict__ w1b,
    bf16* __restrict__ w2b, bf16* __restrict__ pwb,
    float* __restrict__ sums) {
  const int idx = blockIdx.x * 256 + threadIdx.x;  // 65536
  w1b[idx] = (bf16)g_w1[idx];
  w2b[idx] = (bf16)g_w2[idx];
  if (idx < 256 * 64) {
    const int n = idx >> 6, c = idx & 63;
    pwb[idx] = (c < 33) ? (bf16)pe_w[n * 33 + c] : (bf16)0.f;
  }
  if (idx < 2 * DD) sums[idx] = 0.f;
}

// per-lane positional-embedding value for column c (0..32; >32 -> 0)
__device__ __forceinline__ float embval(int c, float pd0, float pd1, float pd2) {
  if (c > 32) return 0.f;
  const int cm = c - 3;
  const int ax = (c < 3) ? c : cm % 3;
  const float pdv = (ax == 0) ? pd0 : ((ax == 1) ? pd1 : pd2);
  if (c < 3) return pdv;
  const int f = cm / 6;
  const float x = pdv * fmaf(7.75f, (float)f, 1.0f);  // linspace(1,32,5)
  return ((cm % 6) < 3) ? __sinf(x) : __cosf(x);
}

// ---------------------------------------------------------------------------
// edge_v9 (verbatim round-0 version, measured 345 us): PTS=2, 3 blocks/CU.
// R2 lesson: PTS=1 halves per-phase ILP and regresses 1.7x despite 2x
// occupancy — keep per-phase MFMA work at PTS=2.
// ---------------------------------------------------------------------------
__global__ __launch_bounds__(256, 3) void edge_v9(
    const float* __restrict__ xyz, const float* __restrict__ feats,
    const bf16* __restrict__ qb, const bf16* __restrict__ kfb,
    const bf16* __restrict__ vfb, const int* __restrict__ knn,
    const bf16* __restrict__ w1b, const float* __restrict__ g_b1,
    const bf16* __restrict__ w2b, const float* __restrict__ g_b2,
    const bf16* __restrict__ pwb, const float* __restrict__ pe_b,
    float* __restrict__ res, float* __restrict__ sums,
    float* __restrict__ sumsq) {
  const int t = threadIdx.x;
  const int lane = t & 63;
  const int wv = t >> 6;
  const int m = lane & 15;
  const int qd = lane >> 4;
  const int row0 = blockIdx.x * PTS;
  const int b = row0 >> 12;

  __shared__ __align__(16) bf16 bufA[PTS][16][SA];        // edges
  __shared__ __align__(16) char un_s[PTS * 16 * SA * 2];  // kf_s | bufB(h)
  bf16(*bufB)[16][SA] = (bf16(*)[16][SA])un_s;
  bf16(*kf_s)[16][SA] = (bf16(*)[16][SA])un_s;
  __shared__ __align__(16) bf16 vf_s[PTS][16][SA];
  __shared__ int js_s[PTS][16];

  if (t < PTS * 16) js_s[t >> 4][t & 15] = knn[(row0 + (t >> 4)) * KK + (t & 15)];
  __syncthreads();

  // ---- stage kf_s and vf_s via 16B vector loads (1024 chunks each) ----
#pragma unroll
  for (int i = 0; i < PTS * 2; ++i) {
    const int e = i * 256 + t;
    const int p = e >> 9, rem = e & 511;
    const int k = rem >> 5, ch = rem & 31;
    const size_t base = ((size_t)(b * NN + js_s[p][k])) * DD + ch * 8;
    *(bf16x8*)&kf_s[p][k][ch * 8] = *(const bf16x8*)(kfb + base);
    *(bf16x8*)&vf_s[p][k][ch * 8] = *(const bf16x8*)(vfb + base);
  }

  // ---- emb A-fragments computed per-lane in registers (no LDS) ----
  const float* xb = xyz + (size_t)b * NN * 3;
  bf16x8 ea0[PTS], ea1[PTS];
#pragma unroll
  for (int p = 0; p < PTS; ++p) {
    const int i = (row0 + p) & (NN - 1);
    const int j = js_s[p][m];  // this lane's neighbor row
    const float pd0 = xb[i * 3 + 0] - xb[j * 3 + 0];
    const float pd1 = xb[i * 3 + 1] - xb[j * 3 + 1];
    const float pd2 = xb[i * 3 + 2] - xb[j * 3 + 2];
#pragma unroll
    for (int jj = 0; jj < 8; ++jj) {
      ea0[p][jj] = (bf16)embval(qd * 8 + jj, pd0, pd1, pd2);
      ea1[p][jj] = (bf16)embval(32 + qd * 8 + jj, pd0, pd1, pd2);
    }
  }
  __syncthreads();  // staging visible

  // ---- phase B: pe MFMA -> bufA = q - kf_s + pe ; pe kept in regs ----
  float pe_r[4][PTS][4];
#pragma unroll
  for (int tt = 0; tt < 4; ++tt) {
    const int n = wv * 64 + tt * 16 + m;
    const bf16x8 b0 = *(const bf16x8*)(pwb + (size_t)n * 64 + qd * 8);
    const bf16x8 b1 = *(const bf16x8*)(pwb + (size_t)n * 64 + 32 + qd * 8);
    const float bias = pe_b[n];
#pragma unroll
    for (int p = 0; p < PTS; ++p) {
      f32x4 c = {bias, bias, bias, bias};
      c = __builtin_amdgcn_mfma_f32_16x16x32_bf16(ea0[p], b0, c, 0, 0, 0);
      c = __builtin_amdgcn_mfma_f32_16x16x32_bf16(ea1[p], b1, c, 0, 0, 0);
      const float qv = (float)qb[(size_t)(row0 + p) * DD + n];
#pragma unroll
      for (int rr = 0; rr < 4; ++rr) {
        const int krow = qd * 4 + rr;
        bufA[p][krow][n] = (bf16)(qv - (float)kf_s[p][krow][n] + c[rr]);
        pe_r[tt][p][rr] = c[rr];
      }
    }
  }
  __syncthreads();  // bufA ready; kf_s dead (union -> bufB safe)

  // ---- layer 1: h = relu(edges @ W1^T + b1), bufA -> bufB ----
  {
    bf16x8 afrag[PTS][8];
#pragma unroll
    for (int p = 0; p < PTS; ++p)
#pragma unroll
      for (int f = 0; f < 8; ++f)
        afrag[p][f] = *(const bf16x8*)&bufA[p][m][f * 32 + qd * 8];
    for (int tt = 0; tt < 4; ++tt) {
      const int n = wv * 64 + tt * 16 + m;
      bf16x8 bfr[8];
#pragma unroll
      for (int f = 0; f < 8; ++f)
        bfr[f] = *(const bf16x8*)(w1b + (size_t)n * DD + f * 32 + qd * 8);
      const float bias = g_b1[n];
#pragma unroll
      for (int p = 0; p < PTS; ++p) {
        f32x4 c = {bias, bias, bias, bias};
#pragma unroll
        for (int f = 0; f < 8; ++f)
          c = __builtin_amdgcn_mfma_f32_16x16x32_bf16(afrag[p][f], bfr[f], c, 0, 0, 0);
#pragma unroll
        for (int rr = 0; rr < 4; ++rr)
          bufB[p][qd * 4 + rr][n] = (bf16)fmaxf(c[rr], 0.f);
      }
    }
  }
  __syncthreads();

  // ---- layer 2 + softmax over k + combine (vf_s + pe_r) + BN stats ----
  {
    bf16x8 afrag[PTS][8];
#pragma unroll
    for (int p = 0; p < PTS; ++p)
#pragma unroll
      for (int f = 0; f < 8; ++f)
        afrag[p][f] = *(const bf16x8*)&bufB[p][m][f * 32 + qd * 8];
#pragma unroll
    for (int tt = 0; tt < 4; ++tt) {
      const int n = wv * 64 + tt * 16 + m;
      bf16x8 bfr[8];
#pragma unroll
      for (int f = 0; f < 8; ++f)
        bfr[f] = *(const bf16x8*)(w2b + (size_t)n * DD + f * 32 + qd * 8);
      const float bias = g_b2[n];
      float bs = 0.f, bs2 = 0.f;
#pragma unroll
      for (int p = 0; p < PTS; ++p) {
        f32x4 c = {bias, bias, bias, bias};
#pragma unroll
        for (int f = 0; f < 8; ++f)
          c = __builtin_amdgcn_mfma_f32_16x16x32_bf16(afrag[p][f], bfr[f], c, 0, 0, 0);
        float mx = fmaxf(fmaxf(c[0], c[1]), fmaxf(c[2], c[3]));
        mx = fmaxf(mx, __shfl_xor(mx, 16));
        mx = fmaxf(mx, __shfl_xor(mx, 32));
        float e[4], den = 0.f;
#pragma unroll
        for (int rr = 0; rr < 4; ++rr) {
          e[rr] = __expf(c[rr] - mx);
          den += e[rr];
        }
        den += __shfl_xor(den, 16);
        den += __shfl_xor(den, 32);
        float num = 0.f;
#pragma unroll
        for (int rr = 0; rr < 4; ++rr) {
          const float vpe =
              (float)vf_s[p][qd * 4 + rr][n] + pe_r[tt][p][rr];
          num += e[rr] * vpe;
        }
        num += __shfl_xor(num, 16);
        num += __shfl_xor(num, 32);
        if (qd == 0) {
          const size_t o = (size_t)(row0 + p) * DD + n;
          const float out = num / den + feats[o];
          res[o] = out;
          bs += out;
          bs2 += out * out;
        }
      }
      if (qd == 0) {
        atomicAdd(&sums[n], bs);
        atomicAdd(&sumsq[n], bs2);
      }
    }
  }
}

// ---------------------------------------------------------------------------
// BatchNorm apply (stats accumulated by edge_v9's epilogue)
// ---------------------------------------------------------------------------
__global__ __launch_bounds__(256) void bn_apply(float* __restrict__ out,
                                                const float* __restrict__ sums,
                                                const float* __restrict__ sumsq,
                                                const float* __restrict__ bn_w,
                                                const float* __restrict__ bn_b) {
  const int idx = blockIdx.x * 256 + threadIdx.x;
  const int c = idx & (DD - 1);
  const float inv_n = 1.f / (float)(BB * NN);
  const float mean = sums[c] * inv_n;
  const float var = sumsq[c] * inv_n - mean * mean;
  const float v = out[idx];
  out[idx] = (v - mean) * rsqrtf(var + 1e-5f) * bn_w[c] + bn_b[c];
}

extern "C" void kernel_launch(void* const* d_in, const int* in_sizes, int n_in,
                              void* d_out, int out_size, void* d_ws,
                              size_t ws_size, hipStream_t stream) {
  (void)in_sizes; (void)n_in; (void)out_size; (void)ws_size;
  const float* xyz = (const float*)d_in[0];
  const float* feats = (const float*)d_in[1];
  const float* w_q = (const float*)d_in[2];
  const float* w_k = (const float*)d_in[3];
  const float* w_v = (const float*)d_in[4];
  const float* g_w1 = (const float*)d_in[5];
  const float* g_b1 = (const float*)d_in[6];
  const float* g_w2 = (const float*)d_in[7];
  const float* g_b2 = (const float*)d_in[8];
  const float* pe_w = (const float*)d_in[9];
  const float* pe_b = (const float*)d_in[10];
  const float* bn_w = (const float*)d_in[11];
  const float* bn_b = (const float*)d_in[12];
  float* out = (float*)d_out;

  const int BN = BB * NN;  // 16384
  char* w = (char*)d_ws;
  int* knn = (int*)w;       w += (size_t)BN * KK * 4;
  bf16* qb = (bf16*)w;      w += (size_t)BN * DD * 2;
  bf16* kfb = (bf16*)w;     w += (size_t)BN * DD * 2;
  bf16* vfb = (bf16*)w;     w += (size_t)BN * DD * 2;
  float* sums = (float*)w;  w += DD * 4;
  float* sumsq = (float*)w; w += DD * 4;
  bf16* w1b = (bf16*)w;     w += (size_t)DD * DD * 2;
  bf16* w2b = (bf16*)w;     w += (size_t)DD * DD * 2;
  bf16* pwb = (bf16*)w;     w += (size_t)DD * 64 * 2;

  knn_kernel<<<KNNB, 256, 0, stream>>>(xyz, knn);
  proj_kernel<<<PROJB, 256, 0, stream>>>(feats, w_q, w_k, w_v, qb, kfb, vfb);
  prep_kernel<<<PREPB, 256, 0, stream>>>(g_w1, g_w2, pe_w, w1b, w2b, pwb,
                                         sums);
  edge_v9<<<BN / PTS, 256, 0, stream>>>(xyz, feats, qb, kfb, vfb, knn, w1b,
                                        g_b1, w2b, g_b2, pwb, pe_b, out, sums,
                                        sumsq);
  bn_apply<<<BN, 256, 0, stream>>>(out, sums, sumsq, bn_w, bn_b);
}

// Round 8
// 753.211 us; speedup vs baseline: 2.1847x; 1.0209x over previous
//
#include <hip/hip_runtime.h>

#define BB 4
#define NN 4096
#define DD 256
#define KK 16
#define PTS 2
#define SA 264   // bufA/bufB/kf row stride (bf16)

typedef __bf16 bf16;
typedef __attribute__((ext_vector_type(8))) __bf16 bf16x8;
typedef __attribute__((ext_vector_type(4))) __bf16 bf16x4;
typedef __attribute__((ext_vector_type(4))) float f32x4;

#define KNNB 4096   // knn blocks (4 points each)
#define PROJB 256   // proj blocks (64 rows each)
#define PREPB 256   // prep blocks

// ---------------------------------------------------------------------------
// setup_kernel — R0 verbatim restore (measured ~263 us for knn+proj+prep,
// passed twice). Fused launch runs all three stages concurrently; the R2-R7
// split serialized them (proj at 1 block/CU on an idle GPU) and the knn
// rewrites introduced the scratch demotion (rule #20) that R0's fully
// unrolled cand[64] at launch_bounds(256,2) (256-VGPR cap -> no spill)
// never had. Lesson logged: don't "fix" an unmeasured branch.
// ---------------------------------------------------------------------------
__global__ __launch_bounds__(256, 2) void setup_kernel(
    const float* __restrict__ xyz, const float* __restrict__ feats,
    const float* __restrict__ w_q, const float* __restrict__ w_k,
    const float* __restrict__ w_v, const float* __restrict__ g_w1,
    const float* __restrict__ g_w2, const float* __restrict__ pe_w,
    int* __restrict__ knn, bf16* __restrict__ qb, bf16* __restrict__ kfb,
    bf16* __restrict__ vfb, bf16* __restrict__ w1b, bf16* __restrict__ w2b,
    bf16* __restrict__ pwb, float* __restrict__ sums) {
  const int bid = blockIdx.x;
  const int t = threadIdx.x;
  __shared__ __align__(16) float smem[NN * 3];  // 48 KB knn / proj fs union

  if (bid < KNNB) {
    const int row0 = bid * 4;
    const int b = row0 >> 12;
    const float* xb = xyz + (size_t)b * NN * 3;
    for (int e = t; e < NN * 3; e += 256) smem[e] = xb[e];
    __syncthreads();
    const int lane = t & 63;
    const int row = row0 + (t >> 6);
    const int i = row & (NN - 1);
    const float xi = smem[i * 3 + 0], yi = smem[i * 3 + 1], zi = smem[i * 3 + 2];
    unsigned long long cand[64];
#pragma unroll
    for (int c = 0; c < 64; ++c) {
      const int j = c * 64 + lane;
      const float dx = xi - smem[j * 3 + 0];
      const float dy = yi - smem[j * 3 + 1];
      const float dz = zi - smem[j * 3 + 2];
      const float d = dx * dx + dy * dy + dz * dz;
      const unsigned long long fb =
          (unsigned long long)(__float_as_uint(d)) + 1ull;
      cand[c] = (fb << 32) | (unsigned int)j;
    }
    unsigned long long gm[8];
#pragma unroll
    for (int g = 0; g < 8; ++g) {
      unsigned long long mn = cand[g * 8];
#pragma unroll
      for (int s = 1; s < 8; ++s)
        if (cand[g * 8 + s] < mn) mn = cand[g * 8 + s];
      gm[g] = mn;
    }
    unsigned int myj = 0u;
    for (int r = 0; r < KK; ++r) {
      unsigned long long lmin = gm[0];
#pragma unroll
      for (int g = 1; g < 8; ++g)
        if (gm[g] < lmin) lmin = gm[g];
#pragma unroll
      for (int off = 1; off < 64; off <<= 1) {
        const unsigned long long o = __shfl_xor(lmin, off);
        if (o < lmin) lmin = o;
      }
      if (lane == r) myj = (unsigned int)lmin;
#pragma unroll
      for (int g = 0; g < 8; ++g) {
        if (__ballot(gm[g] == lmin)) {
          unsigned long long nm = ~0ull;
#pragma unroll
          for (int s = 0; s < 8; ++s) {
            const unsigned long long v = cand[g * 8 + s];
            if (v > lmin && v < nm) nm = v;
          }
          if (gm[g] == lmin) gm[g] = nm;
        }
      }
    }
    if (lane < KK) knn[row * KK + lane] = (int)myj;
    return;
  }
  if (bid < KNNB + PROJB) {
    bf16(*fs)[SA] = (bf16(*)[SA])smem;  // 64*264*2 = 33.8 KB
    const int lane = t & 63, wv = t >> 6;
    const int m = lane & 15, qd = lane >> 4;
    const size_t r0 = (size_t)(bid - KNNB) * 64;
    const float4* f4 = (const float4*)(feats + r0 * DD);
#pragma unroll
    for (int i = 0; i < 16; ++i) {
      const int e = i * 256 + t;
      const float4 v = f4[e];
      bf16x4 w;
      w[0] = (bf16)v.x; w[1] = (bf16)v.y; w[2] = (bf16)v.z; w[3] = (bf16)v.w;
      *(bf16x4*)&fs[e >> 6][(e & 63) * 4] = w;
    }
    __syncthreads();
    bf16x8 afrag[8];
#pragma unroll
    for (int f = 0; f < 8; ++f)
      afrag[f] = *(const bf16x8*)&fs[wv * 16 + m][f * 32 + qd * 8];
    const float* wmat[3] = {w_q, w_k, w_v};
    bf16* omat[3] = {qb, kfb, vfb};
    for (int mat = 0; mat < 3; ++mat) {
      const float* wb = wmat[mat];
      for (int nt = 0; nt < 16; ++nt) {
        const int n = nt * 16 + m;
        bf16x8 bfr[8];
#pragma unroll
        for (int f = 0; f < 8; ++f) {
          const float4 wa =
              *(const float4*)(wb + (size_t)n * DD + f * 32 + qd * 8);
          const float4 wc =
              *(const float4*)(wb + (size_t)n * DD + f * 32 + qd * 8 + 4);
          bf16x8 x;
          x[0] = (bf16)wa.x; x[1] = (bf16)wa.y; x[2] = (bf16)wa.z; x[3] = (bf16)wa.w;
          x[4] = (bf16)wc.x; x[5] = (bf16)wc.y; x[6] = (bf16)wc.z; x[7] = (bf16)wc.w;
          bfr[f] = x;
        }
        f32x4 c = {0.f, 0.f, 0.f, 0.f};
#pragma unroll
        for (int f = 0; f < 8; ++f)
          c = __builtin_amdgcn_mfma_f32_16x16x32_bf16(afrag[f], bfr[f], c, 0, 0, 0);
#pragma unroll
        for (int rr = 0; rr < 4; ++rr)
          omat[mat][(r0 + wv * 16 + qd * 4 + rr) * DD + n] = (bf16)c[rr];
      }
    }
    return;
  }
  {
    const int idx = (bid - (KNNB + PROJB)) * 256 + t;  // 65536
    w1b[idx] = (bf16)g_w1[idx];
    w2b[idx] = (bf16)g_w2[idx];
    if (idx < 256 * 64) {
      const int n = idx >> 6, c = idx & 63;
      pwb[idx] = (c < 33) ? (bf16)pe_w[n * 33 + c] : (bf16)0.f;
    }
    if (idx < 2 * DD) sums[idx] = 0.f;
  }
}

// per-lane positional-embedding value for column c (0..32; >32 -> 0)
__device__ __forceinline__ float embval(int c, float pd0, float pd1, float pd2) {
  if (c > 32) return 0.f;
  const int cm = c - 3;
  const int ax = (c < 3) ? c : cm % 3;
  const float pdv = (ax == 0) ? pd0 : ((ax == 1) ? pd1 : pd2);
  if (c < 3) return pdv;
  const int f = cm / 6;
  const float x = pdv * fmaf(7.75f, (float)f, 1.0f);  // linspace(1,32,5)
  return ((cm % 6) < 3) ? __sinf(x) : __cosf(x);
}

// ---------------------------------------------------------------------------
// edge_v10: v9 dataflow, but vf_s REMOVED from LDS — the epilogue reads vfb
// directly (32B-coalesced per quarter-wave, L2-resident: vfb was written by
// setup this launch). LDS 51.2 -> ~34 KB => 4 blocks/CU (was 3). Unlike the
// failed R2 PTS=1 experiment, per-phase MFMA work is UNCHANGED — this adds
// TLP to cover the 4 barrier drains + gather latency that the R0 profile
// (MfmaUtil 9.2, VALUBusy 22, HBM 4%, occ 33%, no saturated pipe) exposed.
// ---------------------------------------------------------------------------
__global__ __launch_bounds__(256, 4) void edge_v10(
    const float* __restrict__ xyz, const float* __restrict__ feats,
    const bf16* __restrict__ qb, const bf16* __restrict__ kfb,
    const bf16* __restrict__ vfb, const int* __restrict__ knn,
    const bf16* __restrict__ w1b, const float* __restrict__ g_b1,
    const bf16* __restrict__ w2b, const float* __restrict__ g_b2,
    const bf16* __restrict__ pwb, const float* __restrict__ pe_b,
    float* __restrict__ res, float* __restrict__ sums,
    float* __restrict__ sumsq) {
  const int t = threadIdx.x;
  const int lane = t & 63;
  const int wv = t >> 6;
  const int m = lane & 15;
  const int qd = lane >> 4;
  const int row0 = blockIdx.x * PTS;
  const int b = row0 >> 12;

  __shared__ __align__(16) bf16 bufA[PTS][16][SA];        // edges
  __shared__ __align__(16) char un_s[PTS * 16 * SA * 2];  // kf_s | bufB(h)
  bf16(*bufB)[16][SA] = (bf16(*)[16][SA])un_s;
  bf16(*kf_s)[16][SA] = (bf16(*)[16][SA])un_s;
  __shared__ int js_s[PTS][16];

  if (t < PTS * 16) js_s[t >> 4][t & 15] = knn[(row0 + (t >> 4)) * KK + (t & 15)];
  __syncthreads();

  // ---- stage kf_s via 16B vector loads (1024 chunks) ----
#pragma unroll
  for (int i = 0; i < PTS * 2; ++i) {
    const int e = i * 256 + t;
    const int p = e >> 9, rem = e & 511;
    const int k = rem >> 5, ch = rem & 31;
    const size_t base = ((size_t)(b * NN + js_s[p][k])) * DD + ch * 8;
    *(bf16x8*)&kf_s[p][k][ch * 8] = *(const bf16x8*)(kfb + base);
  }

  // ---- emb A-fragments computed per-lane in registers (no LDS) ----
  const float* xb = xyz + (size_t)b * NN * 3;
  bf16x8 ea0[PTS], ea1[PTS];
#pragma unroll
  for (int p = 0; p < PTS; ++p) {
    const int i = (row0 + p) & (NN - 1);
    const int j = js_s[p][m];  // this lane's neighbor row
    const float pd0 = xb[i * 3 + 0] - xb[j * 3 + 0];
    const float pd1 = xb[i * 3 + 1] - xb[j * 3 + 1];
    const float pd2 = xb[i * 3 + 2] - xb[j * 3 + 2];
#pragma unroll
    for (int jj = 0; jj < 8; ++jj) {
      ea0[p][jj] = (bf16)embval(qd * 8 + jj, pd0, pd1, pd2);
      ea1[p][jj] = (bf16)embval(32 + qd * 8 + jj, pd0, pd1, pd2);
    }
  }
  __syncthreads();  // staging visible

  // ---- phase B: pe MFMA -> bufA = q - kf_s + pe ; pe kept in regs ----
  float pe_r[4][PTS][4];
#pragma unroll
  for (int tt = 0; tt < 4; ++tt) {
    const int n = wv * 64 + tt * 16 + m;
    const bf16x8 b0 = *(const bf16x8*)(pwb + (size_t)n * 64 + qd * 8);
    const bf16x8 b1 = *(const bf16x8*)(pwb + (size_t)n * 64 + 32 + qd * 8);
    const float bias = pe_b[n];
#pragma unroll
    for (int p = 0; p < PTS; ++p) {
      f32x4 c = {bias, bias, bias, bias};
      c = __builtin_amdgcn_mfma_f32_16x16x32_bf16(ea0[p], b0, c, 0, 0, 0);
      c = __builtin_amdgcn_mfma_f32_16x16x32_bf16(ea1[p], b1, c, 0, 0, 0);
      const float qv = (float)qb[(size_t)(row0 + p) * DD + n];
#pragma unroll
      for (int rr = 0; rr < 4; ++rr) {
        const int krow = qd * 4 + rr;
        bufA[p][krow][n] = (bf16)(qv - (float)kf_s[p][krow][n] + c[rr]);
        pe_r[tt][p][rr] = c[rr];
      }
    }
  }
  __syncthreads();  // bufA ready; kf_s dead (union -> bufB safe)

  // ---- layer 1: h = relu(edges @ W1^T + b1), bufA -> bufB ----
  {
    bf16x8 afrag[PTS][8];
#pragma unroll
    for (int p = 0; p < PTS; ++p)
#pragma unroll
      for (int f = 0; f < 8; ++f)
        afrag[p][f] = *(const bf16x8*)&bufA[p][m][f * 32 + qd * 8];
    for (int tt = 0; tt < 4; ++tt) {
      const int n = wv * 64 + tt * 16 + m;
      bf16x8 bfr[8];
#pragma unroll
      for (int f = 0; f < 8; ++f)
        bfr[f] = *(const bf16x8*)(w1b + (size_t)n * DD + f * 32 + qd * 8);
      const float bias = g_b1[n];
#pragma unroll
      for (int p = 0; p < PTS; ++p) {
        f32x4 c = {bias, bias, bias, bias};
#pragma unroll
        for (int f = 0; f < 8; ++f)
          c = __builtin_amdgcn_mfma_f32_16x16x32_bf16(afrag[p][f], bfr[f], c, 0, 0, 0);
#pragma unroll
        for (int rr = 0; rr < 4; ++rr)
          bufB[p][qd * 4 + rr][n] = (bf16)fmaxf(c[rr], 0.f);
      }
    }
  }
  __syncthreads();

  // ---- layer 2 + softmax over k + combine (vfb direct + pe_r) + BN ----
  {
    bf16x8 afrag[PTS][8];
#pragma unroll
    for (int p = 0; p < PTS; ++p)
#pragma unroll
      for (int f = 0; f < 8; ++f)
        afrag[p][f] = *(const bf16x8*)&bufB[p][m][f * 32 + qd * 8];
    // hoist neighbor rows for this lane's 4 k-slots (constant across tt)
    int jr[PTS][4];
#pragma unroll
    for (int p = 0; p < PTS; ++p)
#pragma unroll
      for (int rr = 0; rr < 4; ++rr)
        jr[p][rr] = js_s[p][qd * 4 + rr];
#pragma unroll
    for (int tt = 0; tt < 4; ++tt) {
      const int n = wv * 64 + tt * 16 + m;
      bf16x8 bfr[8];
#pragma unroll
      for (int f = 0; f < 8; ++f)
        bfr[f] = *(const bf16x8*)(w2b + (size_t)n * DD + f * 32 + qd * 8);
      const float bias = g_b2[n];
      float bs = 0.f, bs2 = 0.f;
#pragma unroll
      for (int p = 0; p < PTS; ++p) {
        f32x4 c = {bias, bias, bias, bias};
#pragma unroll
        for (int f = 0; f < 8; ++f)
          c = __builtin_amdgcn_mfma_f32_16x16x32_bf16(afrag[p][f], bfr[f], c, 0, 0, 0);
        float mx = fmaxf(fmaxf(c[0], c[1]), fmaxf(c[2], c[3]));
        mx = fmaxf(mx, __shfl_xor(mx, 16));
        mx = fmaxf(mx, __shfl_xor(mx, 32));
        float e[4], den = 0.f;
#pragma unroll
        for (int rr = 0; rr < 4; ++rr) {
          e[rr] = __expf(c[rr] - mx);
          den += e[rr];
        }
        den += __shfl_xor(den, 16);
        den += __shfl_xor(den, 32);
        float num = 0.f;
#pragma unroll
        for (int rr = 0; rr < 4; ++rr) {
          const float vfv =
              (float)vfb[((size_t)(b * NN + jr[p][rr])) * DD + n];
          const float vpe = vfv + pe_r[tt][p][rr];
          num += e[rr] * vpe;
        }
        num += __shfl_xor(num, 16);
        num += __shfl_xor(num, 32);
        if (qd == 0) {
          const size_t o = (size_t)(row0 + p) * DD + n;
          const float out = num / den + feats[o];
          res[o] = out;
          bs += out;
          bs2 += out * out;
        }
      }
      if (qd == 0) {
        atomicAdd(&sums[n], bs);
        atomicAdd(&sumsq[n], bs2);
      }
    }
  }
}

// ---------------------------------------------------------------------------
// BatchNorm apply (stats accumulated by edge_v10's epilogue)
// ---------------------------------------------------------------------------
__global__ __launch_bounds__(256) void bn_apply(float* __restrict__ out,
                                                const float* __restrict__ sums,
                                                const float* __restrict__ sumsq,
                                                const float* __restrict__ bn_w,
                                                const float* __restrict__ bn_b) {
  const int idx = blockIdx.x * 256 + threadIdx.x;
  const int c = idx & (DD - 1);
  const float inv_n = 1.f / (float)(BB * NN);
  const float mean = sums[c] * inv_n;
  const float var = sumsq[c] * inv_n - mean * mean;
  const float v = out[idx];
  out[idx] = (v - mean) * rsqrtf(var + 1e-5f) * bn_w[c] + bn_b[c];
}

extern "C" void kernel_launch(void* const* d_in, const int* in_sizes, int n_in,
                              void* d_out, int out_size, void* d_ws,
                              size_t ws_size, hipStream_t stream) {
  (void)in_sizes; (void)n_in; (void)out_size; (void)ws_size;
  const float* xyz = (const float*)d_in[0];
  const float* feats = (const float*)d_in[1];
  const float* w_q = (const float*)d_in[2];
  const float* w_k = (const float*)d_in[3];
  const float* w_v = (const float*)d_in[4];
  const float* g_w1 = (const float*)d_in[5];
  const float* g_b1 = (const float*)d_in[6];
  const float* g_w2 = (const float*)d_in[7];
  const float* g_b2 = (const float*)d_in[8];
  const float* pe_w = (const float*)d_in[9];
  const float* pe_b = (const float*)d_in[10];
  const float* bn_w = (const float*)d_in[11];
  const float* bn_b = (const float*)d_in[12];
  float* out = (float*)d_out;

  const int BN = BB * NN;  // 16384
  char* w = (char*)d_ws;
  int* knn = (int*)w;       w += (size_t)BN * KK * 4;
  bf16* qb = (bf16*)w;      w += (size_t)BN * DD * 2;
  bf16* kfb = (bf16*)w;     w += (size_t)BN * DD * 2;
  bf16* vfb = (bf16*)w;     w += (size_t)BN * DD * 2;
  float* sums = (float*)w;  w += DD * 4;
  float* sumsq = (float*)w; w += DD * 4;
  bf16* w1b = (bf16*)w;     w += (size_t)DD * DD * 2;
  bf16* w2b = (bf16*)w;     w += (size_t)DD * DD * 2;
  bf16* pwb = (bf16*)w;     w += (size_t)DD * 64 * 2;

  setup_kernel<<<KNNB + PROJB + PREPB, 256, 0, stream>>>(
      xyz, feats, w_q, w_k, w_v, g_w1, g_w2, pe_w, knn, qb, kfb, vfb, w1b, w2b,
      pwb, sums);
  edge_v10<<<BN / PTS, 256, 0, stream>>>(xyz, feats, qb, kfb, vfb, knn, w1b,
                                         g_b1, w2b, g_b2, pwb, pe_b, out, sums,
                                         sumsq);
  bn_apply<<<BN, 256, 0, stream>>>(out, sums, sumsq, bn_w, bn_b);
}

// Round 9
// 663.243 us; speedup vs baseline: 2.4810x; 1.1356x over previous
//
#include <hip/hip_runtime.h>

#define BB 4
#define NN 4096
#define DD 256
#define KK 16
#define PTS 2
#define SA 264   // bufA/bufB/kf row stride (bf16)

typedef __bf16 bf16;
typedef __attribute__((ext_vector_type(8))) __bf16 bf16x8;
typedef __attribute__((ext_vector_type(4))) __bf16 bf16x4;
typedef __attribute__((ext_vector_type(4))) float f32x4;

#define KNNB 4096   // knn blocks (4 points each)
#define PROJB 256   // proj blocks (64 rows each)
#define PREPB 256   // prep blocks

// ---------------------------------------------------------------------------
// setup_kernel — R0 verbatim (measured ~263 us for knn+proj+prep, passed 3x).
// ---------------------------------------------------------------------------
__global__ __launch_bounds__(256, 2) void setup_kernel(
    const float* __restrict__ xyz, const float* __restrict__ feats,
    const float* __restrict__ w_q, const float* __restrict__ w_k,
    const float* __restrict__ w_v, const float* __restrict__ g_w1,
    const float* __restrict__ g_w2, const float* __restrict__ pe_w,
    int* __restrict__ knn, bf16* __restrict__ qb, bf16* __restrict__ kfb,
    bf16* __restrict__ vfb, bf16* __restrict__ w1b, bf16* __restrict__ w2b,
    bf16* __restrict__ pwb, float* __restrict__ sums) {
  const int bid = blockIdx.x;
  const int t = threadIdx.x;
  __shared__ __align__(16) float smem[NN * 3];  // 48 KB knn / proj fs union

  if (bid < KNNB) {
    const int row0 = bid * 4;
    const int b = row0 >> 12;
    const float* xb = xyz + (size_t)b * NN * 3;
    for (int e = t; e < NN * 3; e += 256) smem[e] = xb[e];
    __syncthreads();
    const int lane = t & 63;
    const int row = row0 + (t >> 6);
    const int i = row & (NN - 1);
    const float xi = smem[i * 3 + 0], yi = smem[i * 3 + 1], zi = smem[i * 3 + 2];
    unsigned long long cand[64];
#pragma unroll
    for (int c = 0; c < 64; ++c) {
      const int j = c * 64 + lane;
      const float dx = xi - smem[j * 3 + 0];
      const float dy = yi - smem[j * 3 + 1];
      const float dz = zi - smem[j * 3 + 2];
      const float d = dx * dx + dy * dy + dz * dz;
      const unsigned long long fb =
          (unsigned long long)(__float_as_uint(d)) + 1ull;
      cand[c] = (fb << 32) | (unsigned int)j;
    }
    unsigned long long gm[8];
#pragma unroll
    for (int g = 0; g < 8; ++g) {
      unsigned long long mn = cand[g * 8];
#pragma unroll
      for (int s = 1; s < 8; ++s)
        if (cand[g * 8 + s] < mn) mn = cand[g * 8 + s];
      gm[g] = mn;
    }
    unsigned int myj = 0u;
    for (int r = 0; r < KK; ++r) {
      unsigned long long lmin = gm[0];
#pragma unroll
      for (int g = 1; g < 8; ++g)
        if (gm[g] < lmin) lmin = gm[g];
#pragma unroll
      for (int off = 1; off < 64; off <<= 1) {
        const unsigned long long o = __shfl_xor(lmin, off);
        if (o < lmin) lmin = o;
      }
      if (lane == r) myj = (unsigned int)lmin;
#pragma unroll
      for (int g = 0; g < 8; ++g) {
        if (__ballot(gm[g] == lmin)) {
          unsigned long long nm = ~0ull;
#pragma unroll
          for (int s = 0; s < 8; ++s) {
            const unsigned long long v = cand[g * 8 + s];
            if (v > lmin && v < nm) nm = v;
          }
          if (gm[g] == lmin) gm[g] = nm;
        }
      }
    }
    if (lane < KK) knn[row * KK + lane] = (int)myj;
    return;
  }
  if (bid < KNNB + PROJB) {
    bf16(*fs)[SA] = (bf16(*)[SA])smem;  // 64*264*2 = 33.8 KB
    const int lane = t & 63, wv = t >> 6;
    const int m = lane & 15, qd = lane >> 4;
    const size_t r0 = (size_t)(bid - KNNB) * 64;
    const float4* f4 = (const float4*)(feats + r0 * DD);
#pragma unroll
    for (int i = 0; i < 16; ++i) {
      const int e = i * 256 + t;
      const float4 v = f4[e];
      bf16x4 w;
      w[0] = (bf16)v.x; w[1] = (bf16)v.y; w[2] = (bf16)v.z; w[3] = (bf16)v.w;
      *(bf16x4*)&fs[e >> 6][(e & 63) * 4] = w;
    }
    __syncthreads();
    bf16x8 afrag[8];
#pragma unroll
    for (int f = 0; f < 8; ++f)
      afrag[f] = *(const bf16x8*)&fs[wv * 16 + m][f * 32 + qd * 8];
    const float* wmat[3] = {w_q, w_k, w_v};
    bf16* omat[3] = {qb, kfb, vfb};
    for (int mat = 0; mat < 3; ++mat) {
      const float* wb = wmat[mat];
      for (int nt = 0; nt < 16; ++nt) {
        const int n = nt * 16 + m;
        bf16x8 bfr[8];
#pragma unroll
        for (int f = 0; f < 8; ++f) {
          const float4 wa =
              *(const float4*)(wb + (size_t)n * DD + f * 32 + qd * 8);
          const float4 wc =
              *(const float4*)(wb + (size_t)n * DD + f * 32 + qd * 8 + 4);
          bf16x8 x;
          x[0] = (bf16)wa.x; x[1] = (bf16)wa.y; x[2] = (bf16)wa.z; x[3] = (bf16)wa.w;
          x[4] = (bf16)wc.x; x[5] = (bf16)wc.y; x[6] = (bf16)wc.z; x[7] = (bf16)wc.w;
          bfr[f] = x;
        }
        f32x4 c = {0.f, 0.f, 0.f, 0.f};
#pragma unroll
        for (int f = 0; f < 8; ++f)
          c = __builtin_amdgcn_mfma_f32_16x16x32_bf16(afrag[f], bfr[f], c, 0, 0, 0);
#pragma unroll
        for (int rr = 0; rr < 4; ++rr)
          omat[mat][(r0 + wv * 16 + qd * 4 + rr) * DD + n] = (bf16)c[rr];
      }
    }
    return;
  }
  {
    const int idx = (bid - (KNNB + PROJB)) * 256 + t;  // 65536
    w1b[idx] = (bf16)g_w1[idx];
    w2b[idx] = (bf16)g_w2[idx];
    if (idx < 256 * 64) {
      const int n = idx >> 6, c = idx & 63;
      pwb[idx] = (c < 33) ? (bf16)pe_w[n * 33 + c] : (bf16)0.f;
    }
    if (idx < 2 * DD) sums[idx] = 0.f;
  }
}

// per-lane positional-embedding value for column c (0..32; >32 -> 0)
__device__ __forceinline__ float embval(int c, float pd0, float pd1, float pd2) {
  if (c > 32) return 0.f;
  const int cm = c - 3;
  const int ax = (c < 3) ? c : cm % 3;
  const float pdv = (ax == 0) ? pd0 : ((ax == 1) ? pd1 : pd2);
  if (c < 3) return pdv;
  const int f = cm / 6;
  const float x = pdv * fmaf(7.75f, (float)f, 1.0f);  // linspace(1,32,5)
  return ((cm % 6) < 3) ? __sinf(x) : __cosf(x);
}

// ---------------------------------------------------------------------------
// edge_v10b: R8's v10 body (vf_s dropped from LDS, vfb read direct in the
// epilogue) with __launch_bounds__(256,2). R8 forensics: hipcc's VGPR cap
// ~= 256/w -> w=4 capped at 64 and spilled ~30 regs (~1.3 GB scratch, +140us)
// while the vfb-direct reads themselves added only ~50 MB HBM (L2 absorbed).
// At w=2 the cap is 128: natural ~95 VGPR, no spill; HW rounds 95->128-granule
// -> 4 waves/SIMD = 16 waves/CU, and LDS 34.3 KB -> 4 blocks/CU. Same
// per-phase MFMA work as v9 (R2 lesson), occupancy 3->4 blocks.
// ---------------------------------------------------------------------------
__global__ __launch_bounds__(256, 2) void edge_v10(
    const float* __restrict__ xyz, const float* __restrict__ feats,
    const bf16* __restrict__ qb, const bf16* __restrict__ kfb,
    const bf16* __restrict__ vfb, const int* __restrict__ knn,
    const bf16* __restrict__ w1b, const float* __restrict__ g_b1,
    const bf16* __restrict__ w2b, const float* __restrict__ g_b2,
    const bf16* __restrict__ pwb, const float* __restrict__ pe_b,
    float* __restrict__ res, float* __restrict__ sums,
    float* __restrict__ sumsq) {
  const int t = threadIdx.x;
  const int lane = t & 63;
  const int wv = t >> 6;
  const int m = lane & 15;
  const int qd = lane >> 4;
  const int row0 = blockIdx.x * PTS;
  const int b = row0 >> 12;

  __shared__ __align__(16) bf16 bufA[PTS][16][SA];        // edges
  __shared__ __align__(16) char un_s[PTS * 16 * SA * 2];  // kf_s | bufB(h)
  bf16(*bufB)[16][SA] = (bf16(*)[16][SA])un_s;
  bf16(*kf_s)[16][SA] = (bf16(*)[16][SA])un_s;
  __shared__ int js_s[PTS][16];

  if (t < PTS * 16) js_s[t >> 4][t & 15] = knn[(row0 + (t >> 4)) * KK + (t & 15)];
  __syncthreads();

  // ---- stage kf_s via 16B vector loads (1024 chunks) ----
#pragma unroll
  for (int i = 0; i < PTS * 2; ++i) {
    const int e = i * 256 + t;
    const int p = e >> 9, rem = e & 511;
    const int k = rem >> 5, ch = rem & 31;
    const size_t base = ((size_t)(b * NN + js_s[p][k])) * DD + ch * 8;
    *(bf16x8*)&kf_s[p][k][ch * 8] = *(const bf16x8*)(kfb + base);
  }

  // ---- emb A-fragments computed per-lane in registers (no LDS) ----
  const float* xb = xyz + (size_t)b * NN * 3;
  bf16x8 ea0[PTS], ea1[PTS];
#pragma unroll
  for (int p = 0; p < PTS; ++p) {
    const int i = (row0 + p) & (NN - 1);
    const int j = js_s[p][m];  // this lane's neighbor row
    const float pd0 = xb[i * 3 + 0] - xb[j * 3 + 0];
    const float pd1 = xb[i * 3 + 1] - xb[j * 3 + 1];
    const float pd2 = xb[i * 3 + 2] - xb[j * 3 + 2];
#pragma unroll
    for (int jj = 0; jj < 8; ++jj) {
      ea0[p][jj] = (bf16)embval(qd * 8 + jj, pd0, pd1, pd2);
      ea1[p][jj] = (bf16)embval(32 + qd * 8 + jj, pd0, pd1, pd2);
    }
  }
  __syncthreads();  // staging visible

  // ---- phase B: pe MFMA -> bufA = q - kf_s + pe ; pe kept in regs ----
  float pe_r[4][PTS][4];
#pragma unroll
  for (int tt = 0; tt < 4; ++tt) {
    const int n = wv * 64 + tt * 16 + m;
    const bf16x8 b0 = *(const bf16x8*)(pwb + (size_t)n * 64 + qd * 8);
    const bf16x8 b1 = *(const bf16x8*)(pwb + (size_t)n * 64 + 32 + qd * 8);
    const float bias = pe_b[n];
#pragma unroll
    for (int p = 0; p < PTS; ++p) {
      f32x4 c = {bias, bias, bias, bias};
      c = __builtin_amdgcn_mfma_f32_16x16x32_bf16(ea0[p], b0, c, 0, 0, 0);
      c = __builtin_amdgcn_mfma_f32_16x16x32_bf16(ea1[p], b1, c, 0, 0, 0);
      const float qv = (float)qb[(size_t)(row0 + p) * DD + n];
#pragma unroll
      for (int rr = 0; rr < 4; ++rr) {
        const int krow = qd * 4 + rr;
        bufA[p][krow][n] = (bf16)(qv - (float)kf_s[p][krow][n] + c[rr]);
        pe_r[tt][p][rr] = c[rr];
      }
    }
  }
  __syncthreads();  // bufA ready; kf_s dead (union -> bufB safe)

  // ---- layer 1: h = relu(edges @ W1^T + b1), bufA -> bufB ----
  {
    bf16x8 afrag[PTS][8];
#pragma unroll
    for (int p = 0; p < PTS; ++p)
#pragma unroll
      for (int f = 0; f < 8; ++f)
        afrag[p][f] = *(const bf16x8*)&bufA[p][m][f * 32 + qd * 8];
    for (int tt = 0; tt < 4; ++tt) {
      const int n = wv * 64 + tt * 16 + m;
      bf16x8 bfr[8];
#pragma unroll
      for (int f = 0; f < 8; ++f)
        bfr[f] = *(const bf16x8*)(w1b + (size_t)n * DD + f * 32 + qd * 8);
      const float bias = g_b1[n];
#pragma unroll
      for (int p = 0; p < PTS; ++p) {
        f32x4 c = {bias, bias, bias, bias};
#pragma unroll
        for (int f = 0; f < 8; ++f)
          c = __builtin_amdgcn_mfma_f32_16x16x32_bf16(afrag[p][f], bfr[f], c, 0, 0, 0);
#pragma unroll
        for (int rr = 0; rr < 4; ++rr)
          bufB[p][qd * 4 + rr][n] = (bf16)fmaxf(c[rr], 0.f);
      }
    }
  }
  __syncthreads();

  // ---- layer 2 + softmax over k + combine (vfb direct + pe_r) + BN ----
  {
    bf16x8 afrag[PTS][8];
#pragma unroll
    for (int p = 0; p < PTS; ++p)
#pragma unroll
      for (int f = 0; f < 8; ++f)
        afrag[p][f] = *(const bf16x8*)&bufB[p][m][f * 32 + qd * 8];
    // hoist neighbor rows for this lane's 4 k-slots (constant across tt)
    int jr[PTS][4];
#pragma unroll
    for (int p = 0; p < PTS; ++p)
#pragma unroll
      for (int rr = 0; rr < 4; ++rr)
        jr[p][rr] = js_s[p][qd * 4 + rr];
#pragma unroll
    for (int tt = 0; tt < 4; ++tt) {
      const int n = wv * 64 + tt * 16 + m;
      bf16x8 bfr[8];
#pragma unroll
      for (int f = 0; f < 8; ++f)
        bfr[f] = *(const bf16x8*)(w2b + (size_t)n * DD + f * 32 + qd * 8);
      const float bias = g_b2[n];
      float bs = 0.f, bs2 = 0.f;
#pragma unroll
      for (int p = 0; p < PTS; ++p) {
        f32x4 c = {bias, bias, bias, bias};
#pragma unroll
        for (int f = 0; f < 8; ++f)
          c = __builtin_amdgcn_mfma_f32_16x16x32_bf16(afrag[p][f], bfr[f], c, 0, 0, 0);
        float mx = fmaxf(fmaxf(c[0], c[1]), fmaxf(c[2], c[3]));
        mx = fmaxf(mx, __shfl_xor(mx, 16));
        mx = fmaxf(mx, __shfl_xor(mx, 32));
        float e[4], den = 0.f;
#pragma unroll
        for (int rr = 0; rr < 4; ++rr) {
          e[rr] = __expf(c[rr] - mx);
          den += e[rr];
        }
        den += __shfl_xor(den, 16);
        den += __shfl_xor(den, 32);
        float num = 0.f;
#pragma unroll
        for (int rr = 0; rr < 4; ++rr) {
          const float vfv =
              (float)vfb[((size_t)(b * NN + jr[p][rr])) * DD + n];
          const float vpe = vfv + pe_r[tt][p][rr];
          num += e[rr] * vpe;
        }
        num += __shfl_xor(num, 16);
        num += __shfl_xor(num, 32);
        if (qd == 0) {
          const size_t o = (size_t)(row0 + p) * DD + n;
          const float out = num / den + feats[o];
          res[o] = out;
          bs += out;
          bs2 += out * out;
        }
      }
      if (qd == 0) {
        atomicAdd(&sums[n], bs);
        atomicAdd(&sumsq[n], bs2);
      }
    }
  }
}

// ---------------------------------------------------------------------------
// BatchNorm apply (stats accumulated by edge_v10's epilogue)
// ---------------------------------------------------------------------------
__global__ __launch_bounds__(256) void bn_apply(float* __restrict__ out,
                                                const float* __restrict__ sums,
                                                const float* __restrict__ sumsq,
                                                const float* __restrict__ bn_w,
                                                const float* __restrict__ bn_b) {
  const int idx = blockIdx.x * 256 + threadIdx.x;
  const int c = idx & (DD - 1);
  const float inv_n = 1.f / (float)(BB * NN);
  const float mean = sums[c] * inv_n;
  const float var = sumsq[c] * inv_n - mean * mean;
  const float v = out[idx];
  out[idx] = (v - mean) * rsqrtf(var + 1e-5f) * bn_w[c] + bn_b[c];
}

extern "C" void kernel_launch(void* const* d_in, const int* in_sizes, int n_in,
                              void* d_out, int out_size, void* d_ws,
                              size_t ws_size, hipStream_t stream) {
  (void)in_sizes; (void)n_in; (void)out_size; (void)ws_size;
  const float* xyz = (const float*)d_in[0];
  const float* feats = (const float*)d_in[1];
  const float* w_q = (const float*)d_in[2];
  const float* w_k = (const float*)d_in[3];
  const float* w_v = (const float*)d_in[4];
  const float* g_w1 = (const float*)d_in[5];
  const float* g_b1 = (const float*)d_in[6];
  const float* g_w2 = (const float*)d_in[7];
  const float* g_b2 = (const float*)d_in[8];
  const float* pe_w = (const float*)d_in[9];
  const float* pe_b = (const float*)d_in[10];
  const float* bn_w = (const float*)d_in[11];
  const float* bn_b = (const float*)d_in[12];
  float* out = (float*)d_out;

  const int BN = BB * NN;  // 16384
  char* w = (char*)d_ws;
  int* knn = (int*)w;       w += (size_t)BN * KK * 4;
  bf16* qb = (bf16*)w;      w += (size_t)BN * DD * 2;
  bf16* kfb = (bf16*)w;     w += (size_t)BN * DD * 2;
  bf16* vfb = (bf16*)w;     w += (size_t)BN * DD * 2;
  float* sums = (float*)w;  w += DD * 4;
  float* sumsq = (float*)w; w += DD * 4;
  bf16* w1b = (bf16*)w;     w += (size_t)DD * DD * 2;
  bf16* w2b = (bf16*)w;     w += (size_t)DD * DD * 2;
  bf16* pwb = (bf16*)w;     w += (size_t)DD * 64 * 2;

  setup_kernel<<<KNNB + PROJB + PREPB, 256, 0, stream>>>(
      xyz, feats, w_q, w_k, w_v, g_w1, g_w2, pe_w, knn, qb, kfb, vfb, w1b, w2b,
      pwb, sums);
  edge_v10<<<BN / PTS, 256, 0, stream>>>(xyz, feats, qb, kfb, vfb, knn, w1b,
                                         g_b1, w2b, g_b2, pwb, pe_b, out, sums,
                                         sumsq);
  bn_apply<<<BN, 256, 0, stream>>>(out, sums, sumsq, bn_w, bn_b);
}